// Round 1
// baseline (42.481 us; speedup 1.0000x reference)
//
#include <hip/hip_runtime.h>

// YOLOv1 loss forward, MI355X.
// preds/labels: (16384, 7, 7, 30) fp32, channel-last, cell = 30 contiguous floats.
// Streaming memory-bound: 192.7 MB read -> ~31 us floor at 6.3 TB/s.

#define NCELLS   802816      // 16384*7*7
#define CH       30
#define BLOCK    256
#define NBLOCKS  (NCELLS / BLOCK)   // 3136, exact
#define BATCH    16384.0

__device__ __forceinline__ float sq(float x) { return x * x; }

__device__ __forceinline__ float iou_f(float bx, float by, float bw, float bh,
                                       float lx, float ly, float lw, float lh) {
    float area1 = bw * bh;
    float area2 = lw * lh;
    float max_left  = fmaxf(bx - bw * 0.5f, lx - lw * 0.5f);
    float min_right = fminf(bx + bw * 0.5f, lx + lw * 0.5f);
    float max_top   = fmaxf(by - bh * 0.5f, ly - lh * 0.5f);
    float min_bot   = fminf(by + bh * 0.5f, ly + lh * 0.5f);
    float iw = min_right - max_left;
    float ih = min_bot - max_top;
    float inter = iw * ih;
    float iou = inter / (area1 + area2 - inter);
    return (iw > 0.f && ih > 0.f) ? iou : 0.f;
}

__global__ __launch_bounds__(BLOCK) void yolo_loss_main(
        const float* __restrict__ preds,
        const float* __restrict__ labels,
        float* __restrict__ partials) {
    __shared__ float sp[BLOCK * CH];   // 30720 B
    __shared__ float sl[BLOCK * CH];   // 30720 B
    __shared__ float warp_s[4];

    const int tid = threadIdx.x;
    const long base = (long)blockIdx.x * (BLOCK * CH);   // float index, 16B-aligned offset

    // Stage 256 cells of both arrays via coalesced float4 loads.
    const float4* p4 = reinterpret_cast<const float4*>(preds + base);
    const float4* l4 = reinterpret_cast<const float4*>(labels + base);
    float4* sp4 = reinterpret_cast<float4*>(sp);
    float4* sl4 = reinterpret_cast<float4*>(sl);
    const int NVEC = BLOCK * CH / 4;   // 1920
    #pragma unroll
    for (int i = tid; i < NVEC; i += BLOCK) {
        sp4[i] = p4[i];
        sl4[i] = l4[i];
    }
    __syncthreads();

    const float* P = sp + tid * CH;
    const float* L = sl + tid * CH;

    float p0 = P[0], p1 = P[1], p2 = P[2], p3 = P[3], pc1 = P[4];
    float q0 = P[5], q1 = P[6], q2 = P[7], q3 = P[8], pc2 = P[9];
    float l0 = L[0], l1 = L[1], l2 = L[2], l3 = L[3], lobj = L[4];

    const bool obj = (lobj == 1.0f);

    // class term (channels 10..29)
    float cls = 0.f;
    #pragma unroll
    for (int c = 10; c < CH; ++c) {
        float d = L[c] - P[c];
        cls += d * d;
    }

    float iou1 = iou_f(p0, p1, p2, p3, l0, l1, l2, l3);
    float iou2 = iou_f(q0, q1, q2, q3, l0, l1, l2, l3);
    const bool sel1 = iou1 > iou2;

    float xy1 = sq(l0 - p0) + sq(l1 - p1);
    float xy2 = sq(l0 - q0) + sq(l1 - q1);

    float sl2 = sqrtf(l2), sl3 = sqrtf(l3);
    float wh1 = sq(sl2 - sqrtf(p2)) + sq(sl3 - sqrtf(p3));
    float wh2 = sq(sl2 - sqrtf(q2)) + sq(sl3 - sqrtf(q3));

    float o1 = sq(iou1 - pc1);
    float o2 = sq(iou2 - pc2);

    float n1 = pc2 * pc2;   // sel1 responsible -> penalize other box's conf (p9)
    float n2 = pc1 * pc1;

    float contrib;
    if (obj) {
        float xyt = sel1 ? xy1 : xy2;
        float wht = sel1 ? wh1 : wh2;
        float ot  = sel1 ? o1  : o2;
        float nt  = sel1 ? n1  : n2;
        contrib = 5.0f * xyt + wht + ot + 0.5f * nt + cls;
    } else {
        contrib = 0.5f * (pc1 * pc1 + pc2 * pc2);
    }

    // wave-64 reduction
    float v = contrib;
    #pragma unroll
    for (int off = 32; off > 0; off >>= 1)
        v += __shfl_down(v, off, 64);

    const int wid  = tid >> 6;
    const int lane = tid & 63;
    if (lane == 0) warp_s[wid] = v;
    __syncthreads();
    if (tid == 0)
        partials[blockIdx.x] = warp_s[0] + warp_s[1] + warp_s[2] + warp_s[3];
}

__global__ __launch_bounds__(BLOCK) void yolo_loss_final(
        const float* __restrict__ partials,
        float* __restrict__ out) {
    __shared__ double s[BLOCK];
    double acc = 0.0;
    for (int i = threadIdx.x; i < NBLOCKS; i += BLOCK)
        acc += (double)partials[i];
    s[threadIdx.x] = acc;
    __syncthreads();
    for (int off = BLOCK / 2; off > 0; off >>= 1) {
        if (threadIdx.x < off) s[threadIdx.x] += s[threadIdx.x + off];
        __syncthreads();
    }
    if (threadIdx.x == 0) out[0] = (float)(s[0] / BATCH);
}

extern "C" void kernel_launch(void* const* d_in, const int* in_sizes, int n_in,
                              void* d_out, int out_size, void* d_ws, size_t ws_size,
                              hipStream_t stream) {
    const float* preds  = (const float*)d_in[0];
    const float* labels = (const float*)d_in[1];
    float* out      = (float*)d_out;
    float* partials = (float*)d_ws;   // 3136 floats = 12.5 KB

    yolo_loss_main<<<NBLOCKS, BLOCK, 0, stream>>>(preds, labels, partials);
    yolo_loss_final<<<1, BLOCK, 0, stream>>>(partials, out);
}